// Round 7
// baseline (11026.308 us; speedup 1.0000x reference)
//
#include <hip/hip_runtime.h>
#include <hip/hip_bf16.h>

#define DOF 69
#define NL 6
#define NH 8
#define DMODEL 512
#define DFF 2048
#define HD 64
#define BB 8
#define TT 512
#define MTOK (BB*TT)   // 4096

// workspace layout (bytes) — 24.5 MB total
#define E_OFF     4096u
#define H_OFF     (512u*1024u)
#define HN_OFF    (H_OFF + 8u*1024u*1024u)
#define Q_OFF     (HN_OFF + 4u*1024u*1024u)
#define K_OFF     (Q_OFF + 4u*1024u*1024u)
#define V_OFF     (K_OFF + 4u*1024u*1024u)

typedef const float* fp32p;
typedef __hip_bfloat16 bf16;
typedef const bf16* bf16p;

__device__ __forceinline__ float b2f(bf16 x){ return __bfloat162float(x); }
__device__ __forceinline__ float2 bfpair(unsigned int u){
    union { unsigned int i; float f; } a, b;
    a.i = u << 16; b.i = u & 0xffff0000u;
    return make_float2(a.f, b.f);
}

// ---------------- concat(x, mask) fp32 -> bf16 ----------------
__global__ __launch_bounds__(256)
void k_concat(fp32p x, fp32p mask, bf16* __restrict__ out){
    int idx = blockIdx.x*256 + threadIdx.x;
    if (idx >= MTOK*2*DOF) return;
    int row = idx / (2*DOF), c = idx - row*(2*DOF);
    float v = (c < DOF) ? x[(size_t)row*DOF + c] : mask[(size_t)row*DOF + (c-DOF)];
    out[idx] = __float2bfloat16(v);
}

// ---------------- cast fp32 -> bf16 ----------------
__global__ __launch_bounds__(256)
void k_cast(const float* __restrict__ in, bf16* __restrict__ out){
    int idx = blockIdx.x*256 + threadIdx.x;
    if (idx >= MTOK*DMODEL) return;
    out[idx] = __float2bfloat16(in[idx]);
}

// ---------------- GEMM: C = epi(A @ B[boff..] + bias[biasoff..]) ----------------
// A: bf16 (M x K) lda ; B: fp32 weights + element offset boff, ldb ; fp32 accum.
template<int PRELU, int RESID, int HASBIAS, int OUTF32>
__global__ __launch_bounds__(256)
void k_gemm(bf16p A, int lda,
            fp32p Bw, size_t boff, int ldb,
            fp32p bias, size_t biasoff,
            fp32p alpha, size_t aidx,
            const float* __restrict__ resid,
            void* __restrict__ Cout, int ldc,
            int M, int N, int K)
{
    __shared__ float As[16][64];
    __shared__ float Bs[16][65];
    const int tid = threadIdx.x;
    const int tx = tid & 15, ty = tid >> 4;
    const int bm = blockIdx.y * 64, bn = blockIdx.x * 64;
    float acc[4][4] = {};
    for (int k0 = 0; k0 < K; k0 += 16) {
        #pragma unroll
        for (int idx = tid; idx < 1024; idx += 256) {
            int m = idx >> 4, kk = idx & 15;
            int gk = k0 + kk;
            As[kk][m] = (gk < K) ? b2f(A[(size_t)(bm+m)*lda + gk]) : 0.f;
        }
        #pragma unroll
        for (int idx = tid; idx < 1024; idx += 256) {
            int kk = idx >> 6, n = idx & 63;
            int gk = k0 + kk;
            Bs[kk][n] = (gk < K && bn+n < N) ? Bw[boff + (size_t)gk*ldb + bn + n] : 0.f;
        }
        __syncthreads();
        #pragma unroll
        for (int kk = 0; kk < 16; ++kk) {
            float a0=As[kk][ty], a1=As[kk][ty+16], a2=As[kk][ty+32], a3=As[kk][ty+48];
            float b0=Bs[kk][tx], b1=Bs[kk][tx+16], b2=Bs[kk][tx+32], b3=Bs[kk][tx+48];
            acc[0][0]+=a0*b0; acc[0][1]+=a0*b1; acc[0][2]+=a0*b2; acc[0][3]+=a0*b3;
            acc[1][0]+=a1*b0; acc[1][1]+=a1*b1; acc[1][2]+=a1*b2; acc[1][3]+=a1*b3;
            acc[2][0]+=a2*b0; acc[2][1]+=a2*b1; acc[2][2]+=a2*b2; acc[2][3]+=a2*b3;
            acc[3][0]+=a3*b0; acc[3][1]+=a3*b1; acc[3][2]+=a3*b2; acc[3][3]+=a3*b3;
        }
        __syncthreads();
    }
    float alp = PRELU ? alpha[aidx] : 0.f;
    #pragma unroll
    for (int i = 0; i < 4; ++i) {
        #pragma unroll
        for (int j = 0; j < 4; ++j) {
            int m = bm + ty + 16*i, n = bn + tx + 16*j;
            if (n < N) {
                float c = acc[i][j];
                if (HASBIAS) c += bias[biasoff + n];
                if (PRELU) c = (c >= 0.f) ? c : alp*c;
                if (RESID) c += resid[(size_t)m*ldc + n];
                if (OUTF32) ((float*)Cout)[(size_t)m*ldc + n] = c;
                else ((bf16*)Cout)[(size_t)m*ldc + n] = __float2bfloat16(c);
            }
        }
    }
}

// ---------------- LayerNorm: fp32 in -> bf16 out ----------------
__global__ __launch_bounds__(256)
void k_layernorm(const float* __restrict__ x, fp32p g, fp32p b, bf16* __restrict__ out){
    __shared__ float red[256];
    const int row = blockIdx.x, tid = threadIdx.x;
    const float* xr = x + (size_t)row*DMODEL;
    float x0 = xr[tid], x1 = xr[tid+256];
    red[tid] = x0 + x1; __syncthreads();
    for (int o = 128; o > 0; o >>= 1) { if (tid < o) red[tid] += red[tid+o]; __syncthreads(); }
    float mean = red[0] * (1.f/DMODEL);
    __syncthreads();
    float d0 = x0 - mean, d1 = x1 - mean;
    red[tid] = d0*d0 + d1*d1; __syncthreads();
    for (int o = 128; o > 0; o >>= 1) { if (tid < o) red[tid] += red[tid+o]; __syncthreads(); }
    float inv = rsqrtf(red[0]*(1.f/DMODEL) + 1e-6f);
    out[(size_t)row*DMODEL + tid]     = __float2bfloat16(d0*inv*g[tid]     + b[tid]);
    out[(size_t)row*DMODEL + tid+256] = __float2bfloat16(d1*inv*g[tid+256] + b[tid+256]);
}

// ---------------- relative embedding E: (2T-1, HD) fp32 ----------------
__global__ __launch_bounds__(64)
void k_relemb(fp32p w1, fp32p b1, fp32p a, fp32p w2, fp32p b2, float* __restrict__ E){
    __shared__ float sH[DMODEL];
    const int r = blockIdx.x, tid = threadIdx.x;
    const float dist = (float)(r - (TT-1));
    const float al = a[0];
    for (int d = tid; d < DMODEL; d += 64) {
        float hv = dist * w1[d] + b1[d];
        sH[d] = (hv >= 0.f) ? hv : al*hv;
    }
    __syncthreads();
    float acc = b2[tid];
    for (int d = 0; d < DMODEL; ++d) acc += sH[d] * w2[(size_t)d*HD + tid];
    E[r*HD + tid] = acc;
}

// ---------------- attention with relative-position skew ----------------
__global__ __launch_bounds__(256)
void k_attn(bf16p q, bf16p k, bf16p v, const float* __restrict__ E,
            bf16* __restrict__ o)
{
    __shared__ float sQ[4][HD];
    __shared__ float sP[4][TT];
    const int bid = blockIdx.x;
    const int itile = bid & 127;
    const int h = (bid >> 7) & 7;
    const int b = bid >> 10;
    const int tid = threadIdx.x;
    const int w = tid >> 6, lane = tid & 63;
    const int i = itile*4 + w;
    const size_t qoff = ((size_t)(b*TT + i)*DMODEL) + h*HD;
    sQ[w][lane] = b2f(q[qoff + lane]);
    __syncthreads();

    float sv[8];
    float mx = -1e30f;
    #pragma unroll
    for (int jj = 0; jj < 8; ++jj) {
        int j = jj*64 + lane;
        const uint4* kr = (const uint4*)(k + ((size_t)(b*TT + j)*DMODEL) + h*HD);
        const float4* er = (const float4*)(E + (size_t)(j - i + TT - 1)*HD);
        float s = 0.f;
        #pragma unroll
        for (int c8 = 0; c8 < 8; ++c8) {
            uint4 kv = kr[c8];
            float4 e0 = er[2*c8], e1 = er[2*c8+1];
            float2 k0 = bfpair(kv.x), k1 = bfpair(kv.y), k2 = bfpair(kv.z), k3 = bfpair(kv.w);
            const float* qp = &sQ[w][8*c8];
            s += qp[0]*(k0.x+e0.x) + qp[1]*(k0.y+e0.y)
               + qp[2]*(k1.x+e0.z) + qp[3]*(k1.y+e0.w)
               + qp[4]*(k2.x+e1.x) + qp[5]*(k2.y+e1.y)
               + qp[6]*(k3.x+e1.z) + qp[7]*(k3.y+e1.w);
        }
        sv[jj] = s;
        mx = fmaxf(mx, s);
    }
    #pragma unroll
    for (int m = 1; m < 64; m <<= 1) mx = fmaxf(mx, __shfl_xor(mx, m));
    const float scale = 0.125f;
    float sum = 0.f;
    #pragma unroll
    for (int jj = 0; jj < 8; ++jj) {
        float p = expf((sv[jj] - mx)*scale);
        sP[w][jj*64 + lane] = p;
        sum += p;
    }
    #pragma unroll
    for (int m = 1; m < 64; m <<= 1) sum += __shfl_xor(sum, m);
    const float inv = 1.f / sum;
    float acc = 0.f;
    for (int j = 0; j < TT; ++j)
        acc += sP[w][j] * b2f(v[((size_t)(b*TT + j)*DMODEL) + h*HD + lane]);
    o[qoff + lane] = __float2bfloat16(acc * inv);
}

// ---------------- output split + sigmoid (FP32 out) ----------------
__global__ __launch_bounds__(256)
void k_out(const float* __restrict__ y, float* __restrict__ out){
    int idx = blockIdx.x*256 + threadIdx.x;
    if (idx >= MTOK*73) return;
    int row = idx / 73, c = idx - row*73;
    float val = y[idx];
    if (c < DOF) out[(size_t)row*DOF + c] = val;
    else out[(size_t)MTOK*DOF + row*4 + (c-DOF)] = 1.f/(1.f + expf(-val));
}

extern "C" void kernel_launch(void* const* d_in, const int* in_sizes, int n_in,
                              void* d_out, int out_size, void* d_ws, size_t ws_size,
                              hipStream_t stream)
{
    fp32p x      = (fp32p)d_in[0];
    fp32p mask   = (fp32p)d_in[1];
    fp32p enc_w1 = (fp32p)d_in[2];
    fp32p enc_b1 = (fp32p)d_in[3];
    fp32p enc_a1 = (fp32p)d_in[4];
    fp32p enc_w2 = (fp32p)d_in[5];
    fp32p enc_b2 = (fp32p)d_in[6];
    fp32p enc_a2 = (fp32p)d_in[7];
    fp32p rel_w1 = (fp32p)d_in[8];
    fp32p rel_b1 = (fp32p)d_in[9];
    fp32p rel_a  = (fp32p)d_in[10];
    fp32p rel_w2 = (fp32p)d_in[11];
    fp32p rel_b2 = (fp32p)d_in[12];
    fp32p ln_g   = (fp32p)d_in[13];
    fp32p ln_b   = (fp32p)d_in[14];
    fp32p wq     = (fp32p)d_in[15];
    fp32p bq     = (fp32p)d_in[16];
    fp32p wk     = (fp32p)d_in[17];
    fp32p bk     = (fp32p)d_in[18];
    fp32p wv     = (fp32p)d_in[19];
    fp32p bv     = (fp32p)d_in[20];
    fp32p wo     = (fp32p)d_in[21];
    fp32p bo     = (fp32p)d_in[22];
    fp32p fw1    = (fp32p)d_in[23];
    fp32p fb1    = (fp32p)d_in[24];
    fp32p fa     = (fp32p)d_in[25];
    fp32p fw2    = (fp32p)d_in[26];
    fp32p fb2    = (fp32p)d_in[27];
    fp32p dec_w1 = (fp32p)d_in[28];
    fp32p dec_b1 = (fp32p)d_in[29];
    fp32p dec_a  = (fp32p)d_in[30];
    fp32p dec_w2 = (fp32p)d_in[31];
    fp32p dec_b2 = (fp32p)d_in[32];

    char* wsb = (char*)d_ws;
    float* E   = (float*)(wsb + E_OFF);
    float* h   = (float*)(wsb + H_OFF);
    bf16*  hn  = (bf16*)(wsb + HN_OFF);
    bf16*  q   = (bf16*)(wsb + Q_OFF);
    bf16*  k   = (bf16*)(wsb + K_OFF);
    bf16*  v   = (bf16*)(wsb + V_OFF);
    bf16*  cat = q;            // encoder scratch (q slot free)
    bf16*  mid = q;            // ffn half, spans q+k slots (8 MB)
    bf16*  hb  = v;            // decoder bf16 cast of h
    float* y   = (float*)q;    // decoder logits fp32 (1.17 MB)

    dim3 gD(DMODEL/64, MTOK/64);
    dim3 gF(1024/64, MTOK/64);

    // encoder
    k_concat<<<(MTOK*2*DOF+255)/256, 256, 0, stream>>>(x, mask, cat);
    k_gemm<1,0,1,0><<<gD,256,0,stream>>>(cat, 2*DOF, enc_w1, 0, DMODEL, enc_b1, 0, enc_a1, 0, nullptr, hn, DMODEL, MTOK, DMODEL, 2*DOF);
    k_gemm<1,0,1,1><<<gD,256,0,stream>>>(hn, DMODEL, enc_w2, 0, DMODEL, enc_b2, 0, enc_a2, 0, nullptr, h, DMODEL, MTOK, DMODEL, DMODEL);
    k_relemb<<<2*TT-1, 64, 0, stream>>>(rel_w1, rel_b1, rel_a, rel_w2, rel_b2, E);

    for (int l = 0; l < NL; ++l) {
        size_t oW  = (size_t)l*DMODEL*DMODEL;
        size_t oB  = (size_t)l*DMODEL;
        size_t oF1 = (size_t)l*DMODEL*DFF;
        size_t oBF1= (size_t)l*DFF;
        size_t oF2 = (size_t)l*DFF*DMODEL;

        k_layernorm<<<MTOK, 256, 0, stream>>>(h, ln_g, ln_b, hn);
        k_gemm<0,0,1,0><<<gD,256,0,stream>>>(hn, DMODEL, wq, oW, DMODEL, bq, oB, nullptr, 0, nullptr, q, DMODEL, MTOK, DMODEL, DMODEL);
        k_gemm<0,0,1,0><<<gD,256,0,stream>>>(hn, DMODEL, wk, oW, DMODEL, bk, oB, nullptr, 0, nullptr, k, DMODEL, MTOK, DMODEL, DMODEL);
        k_gemm<0,0,1,0><<<gD,256,0,stream>>>(hn, DMODEL, wv, oW, DMODEL, bv, oB, nullptr, 0, nullptr, v, DMODEL, MTOK, DMODEL, DMODEL);
        k_attn<<<BB*NH*(TT/4), 256, 0, stream>>>(q, k, v, E, hn);
        k_gemm<0,1,1,1><<<gD,256,0,stream>>>(hn, DMODEL, wo, oW, DMODEL, bo, oB, nullptr, 0, h, h, DMODEL, MTOK, DMODEL, DMODEL);
        k_layernorm<<<MTOK, 256, 0, stream>>>(h, ln_g, ln_b, hn);
        k_gemm<1,0,1,0><<<gF,256,0,stream>>>(hn, DMODEL, fw1, oF1, DFF, fb1, oBF1, fa, (size_t)l, nullptr, mid, 1024, MTOK, 1024, DMODEL);
        k_gemm<0,1,1,1><<<gD,256,0,stream>>>(mid, 1024, fw2, oF2, DMODEL, fb2, oB, nullptr, 0, h, h, DMODEL, MTOK, DMODEL, 1024);
        k_gemm<1,0,1,0><<<gF,256,0,stream>>>(hn, DMODEL, fw1, oF1 + 1024, DFF, fb1, oBF1 + 1024, fa, (size_t)l, nullptr, mid, 1024, MTOK, 1024, DMODEL);
        k_gemm<0,1,0,1><<<gD,256,0,stream>>>(mid, 1024, fw2, oF2 + (size_t)1024*DMODEL, DMODEL, nullptr, 0, nullptr, 0, h, h, DMODEL, MTOK, DMODEL, 1024);
    }

    // decoder
    k_cast<<<(MTOK*DMODEL+255)/256, 256, 0, stream>>>(h, hb);
    k_gemm<1,0,1,0><<<gD,256,0,stream>>>(hb, DMODEL, dec_w1, 0, DMODEL, dec_b1, 0, dec_a, 0, nullptr, hn, DMODEL, MTOK, DMODEL, DMODEL);
    {
        dim3 g2((DOF+4+63)/64, MTOK/64);
        k_gemm<0,0,1,1><<<g2,256,0,stream>>>(hn, DMODEL, dec_w2, 0, DOF+4, dec_b2, 0, nullptr, 0, nullptr, y, DOF+4, MTOK, DOF+4, DMODEL);
    }
    k_out<<<(MTOK*73+255)/256, 256, 0, stream>>>(y, (float*)d_out);
}

// Round 8
// 6524.256 us; speedup vs baseline: 1.6900x; 1.6900x over previous
//
#include <hip/hip_runtime.h>
#include <hip/hip_bf16.h>

#define DOF 69
#define NL 6
#define NH 8
#define DMODEL 512
#define DFF 2048
#define HD 64
#define BB 8
#define TT 512
#define MTOK (BB*TT)   // 4096
#define EROWS 1040     // 2T-1 = 1023, padded to cover rbase+95 <= 1039

// workspace layout (bytes) — 24.5 MB total
#define E_OFF     4096u
#define H_OFF     (512u*1024u)
#define HN_OFF    (H_OFF + 8u*1024u*1024u)
#define Q_OFF     (HN_OFF + 4u*1024u*1024u)
#define K_OFF     (Q_OFF + 4u*1024u*1024u)
#define V_OFF     (K_OFF + 4u*1024u*1024u)

typedef const float* fp32p;
typedef __hip_bfloat16 bf16;
typedef const bf16* bf16p;
typedef __attribute__((ext_vector_type(8))) short bf16x8;  // 8 bf16 (4 VGPRs)
typedef __attribute__((ext_vector_type(4))) float f32x4;   // 4 fp32 acc

__device__ __forceinline__ float b2f(bf16 x){ return __bfloat162float(x); }

// ---------------- concat(x, mask) fp32 -> bf16 ----------------
__global__ __launch_bounds__(256)
void k_concat(fp32p x, fp32p mask, bf16* __restrict__ out){
    int idx = blockIdx.x*256 + threadIdx.x;
    if (idx >= MTOK*2*DOF) return;
    int row = idx / (2*DOF), c = idx - row*(2*DOF);
    float v = (c < DOF) ? x[(size_t)row*DOF + c] : mask[(size_t)row*DOF + (c-DOF)];
    out[idx] = __float2bfloat16(v);
}

// ---------------- cast fp32 -> bf16 ----------------
__global__ __launch_bounds__(256)
void k_cast(const float* __restrict__ in, bf16* __restrict__ out){
    int idx = blockIdx.x*256 + threadIdx.x;
    if (idx >= MTOK*DMODEL) return;
    out[idx] = __float2bfloat16(in[idx]);
}

// ---------------- GEMM: C = epi(A @ B[boff..] + bias[biasoff..]) ----------------
template<int PRELU, int RESID, int HASBIAS, int OUTF32>
__global__ __launch_bounds__(256)
void k_gemm(bf16p A, int lda,
            fp32p Bw, size_t boff, int ldb,
            fp32p bias, size_t biasoff,
            fp32p alpha, size_t aidx,
            const float* __restrict__ resid,
            void* __restrict__ Cout, int ldc,
            int M, int N, int K)
{
    __shared__ float As[16][64];
    __shared__ float Bs[16][65];
    const int tid = threadIdx.x;
    const int tx = tid & 15, ty = tid >> 4;
    const int bm = blockIdx.y * 64, bn = blockIdx.x * 64;
    float acc[4][4] = {};
    for (int k0 = 0; k0 < K; k0 += 16) {
        #pragma unroll
        for (int idx = tid; idx < 1024; idx += 256) {
            int m = idx >> 4, kk = idx & 15;
            int gk = k0 + kk;
            As[kk][m] = (gk < K) ? b2f(A[(size_t)(bm+m)*lda + gk]) : 0.f;
        }
        #pragma unroll
        for (int idx = tid; idx < 1024; idx += 256) {
            int kk = idx >> 6, n = idx & 63;
            int gk = k0 + kk;
            Bs[kk][n] = (gk < K && bn+n < N) ? Bw[boff + (size_t)gk*ldb + bn + n] : 0.f;
        }
        __syncthreads();
        #pragma unroll
        for (int kk = 0; kk < 16; ++kk) {
            float a0=As[kk][ty], a1=As[kk][ty+16], a2=As[kk][ty+32], a3=As[kk][ty+48];
            float b0=Bs[kk][tx], b1=Bs[kk][tx+16], b2=Bs[kk][tx+32], b3=Bs[kk][tx+48];
            acc[0][0]+=a0*b0; acc[0][1]+=a0*b1; acc[0][2]+=a0*b2; acc[0][3]+=a0*b3;
            acc[1][0]+=a1*b0; acc[1][1]+=a1*b1; acc[1][2]+=a1*b2; acc[1][3]+=a1*b3;
            acc[2][0]+=a2*b0; acc[2][1]+=a2*b1; acc[2][2]+=a2*b2; acc[2][3]+=a2*b3;
            acc[3][0]+=a3*b0; acc[3][1]+=a3*b1; acc[3][2]+=a3*b2; acc[3][3]+=a3*b3;
        }
        __syncthreads();
    }
    float alp = PRELU ? alpha[aidx] : 0.f;
    #pragma unroll
    for (int i = 0; i < 4; ++i) {
        #pragma unroll
        for (int j = 0; j < 4; ++j) {
            int m = bm + ty + 16*i, n = bn + tx + 16*j;
            if (n < N) {
                float c = acc[i][j];
                if (HASBIAS) c += bias[biasoff + n];
                if (PRELU) c = (c >= 0.f) ? c : alp*c;
                if (RESID) c += resid[(size_t)m*ldc + n];
                if (OUTF32) ((float*)Cout)[(size_t)m*ldc + n] = c;
                else ((bf16*)Cout)[(size_t)m*ldc + n] = __float2bfloat16(c);
            }
        }
    }
}

// ---------------- LayerNorm: fp32 in -> bf16 out ----------------
__global__ __launch_bounds__(256)
void k_layernorm(const float* __restrict__ x, fp32p g, fp32p b, bf16* __restrict__ out){
    __shared__ float red[256];
    const int row = blockIdx.x, tid = threadIdx.x;
    const float* xr = x + (size_t)row*DMODEL;
    float x0 = xr[tid], x1 = xr[tid+256];
    red[tid] = x0 + x1; __syncthreads();
    for (int o = 128; o > 0; o >>= 1) { if (tid < o) red[tid] += red[tid+o]; __syncthreads(); }
    float mean = red[0] * (1.f/DMODEL);
    __syncthreads();
    float d0 = x0 - mean, d1 = x1 - mean;
    red[tid] = d0*d0 + d1*d1; __syncthreads();
    for (int o = 128; o > 0; o >>= 1) { if (tid < o) red[tid] += red[tid+o]; __syncthreads(); }
    float inv = rsqrtf(red[0]*(1.f/DMODEL) + 1e-6f);
    out[(size_t)row*DMODEL + tid]     = __float2bfloat16(d0*inv*g[tid]     + b[tid]);
    out[(size_t)row*DMODEL + tid+256] = __float2bfloat16(d1*inv*g[tid+256] + b[tid+256]);
}

// ---------------- relative embedding E: (EROWS, HD) bf16, zero-padded ----------------
__global__ __launch_bounds__(64)
void k_relemb(fp32p w1, fp32p b1, fp32p a, fp32p w2, fp32p b2, bf16* __restrict__ Ebf){
    __shared__ float sH[DMODEL];
    const int r = blockIdx.x, tid = threadIdx.x;
    if (r >= 2*TT - 1) { Ebf[(size_t)r*HD + tid] = __float2bfloat16(0.f); return; }
    const float dist = (float)(r - (TT-1));
    const float al = a[0];
    for (int d = tid; d < DMODEL; d += 64) {
        float hv = dist * w1[d] + b1[d];
        sH[d] = (hv >= 0.f) ? hv : al*hv;
    }
    __syncthreads();
    float acc = b2[tid];
    for (int d = 0; d < DMODEL; ++d) acc += sH[d] * w2[(size_t)d*HD + tid];
    Ebf[(size_t)r*HD + tid] = __float2bfloat16(acc);
}

// ---------------- MFMA flash attention with relative-position skew ----------------
// block = (b, h, 64-row i-tile); 4 waves, wave owns 16 i-rows.
// S = Q K^T + gather(Q E^T); online softmax; O = P V.
// Layouts (gfx950 16x16x32 bf16, learn_hip m89/m120-verified):
//   A[m=lane&15][k=quad*8+e], B[k=quad*8+e][n=lane&15], C row=quad*4+reg col=lane&15
__global__ __launch_bounds__(256)
void k_attn(bf16p q, bf16p k, bf16p v, bf16p Ebf, bf16* __restrict__ o)
{
    __shared__ bf16  sVT[64][68];        // V^T tile: [d][j_local]
    __shared__ float sQE[4][16][100];    // per-wave qe tile (pitch 100 dwords)
    __shared__ bf16  sP[4][16][68];      // per-wave P tile [i_loc][j_local]

    const int bid  = blockIdx.x;
    const int itile = bid & 7;
    const int h    = (bid >> 3) & 7;
    const int b    = bid >> 6;
    const int tid  = threadIdx.x;
    const int w    = tid >> 6;
    const int lane = tid & 63;
    const int qd   = lane >> 4;       // quad 0..3
    const int cl   = lane & 15;       // col-in-tile

    const int I = itile*64 + w*16;    // wave's first Q row
    const size_t bh = ((size_t)b*TT)*DMODEL + (size_t)h*HD;

    // Q A-frags (held for whole kernel): k-chunks d=[0,32) and [32,64)
    bf16x8 qa0, qa1;
    {
        const bf16* qrow = q + bh + (size_t)(I + cl)*DMODEL;
        qa0 = *(const bf16x8*)(qrow + qd*8);
        qa1 = *(const bf16x8*)(qrow + 32 + qd*8);
    }

    f32x4 Oacc[4] = {};                // 4 d-subtiles of O (C-layout)
    float m_i[4], l_i[4];
    #pragma unroll
    for (int r = 0; r < 4; ++r) { m_i[r] = -1e30f; l_i[r] = 0.f; }
    const float scale = 0.125f;        // 1/sqrt(64)

    for (int J = 0; J < TT; J += 64) {
        // ---- stage V^T (transpose into LDS, coalesced global reads) ----
        {
            int j = tid >> 2, dc = (tid & 3) * 16;
            const bf16* vrow = v + bh + (size_t)(J + j)*DMODEL + dc;
            bf16x8 v0 = *(const bf16x8*)(vrow);
            bf16x8 v1 = *(const bf16x8*)(vrow + 8);
            #pragma unroll
            for (int e = 0; e < 8; ++e) sVT[dc + e][j]     = ((const bf16*)&v0)[e];
            #pragma unroll
            for (int e = 0; e < 8; ++e) sVT[dc + 8 + e][j] = ((const bf16*)&v1)[e];
        }
        __syncthreads();

        // ---- S = Q K^T (4 j-subtiles x 2 k-steps) ----
        f32x4 S[4];
        #pragma unroll
        for (int js = 0; js < 4; ++js) {
            const bf16* krow = k + bh + (size_t)(J + js*16 + cl)*DMODEL;
            bf16x8 kb0 = *(const bf16x8*)(krow + qd*8);
            bf16x8 kb1 = *(const bf16x8*)(krow + 32 + qd*8);
            f32x4 acc = {};
            acc = __builtin_amdgcn_mfma_f32_16x16x32_bf16(qa0, kb0, acc, 0, 0, 0);
            acc = __builtin_amdgcn_mfma_f32_16x16x32_bf16(qa1, kb1, acc, 0, 0, 0);
            S[js] = acc;
        }

        // ---- qe tile: rows I..I+15, cols rbase..rbase+95 ----
        const int rbase = J - I + 496;   // in [0, 944]
        #pragma unroll
        for (int nt = 0; nt < 6; ++nt) {
            const bf16* erow = Ebf + (size_t)(rbase + nt*16 + cl)*HD;
            bf16x8 eb0 = *(const bf16x8*)(erow + qd*8);
            bf16x8 eb1 = *(const bf16x8*)(erow + 32 + qd*8);
            f32x4 acc = {};
            acc = __builtin_amdgcn_mfma_f32_16x16x32_bf16(qa0, eb0, acc, 0, 0, 0);
            acc = __builtin_amdgcn_mfma_f32_16x16x32_bf16(qa1, eb1, acc, 0, 0, 0);
            #pragma unroll
            for (int r = 0; r < 4; ++r)
                sQE[w][qd*4 + r][nt*16 + cl] = acc[r];
        }
        // per-wave LDS RAW: compiler inserts lgkmcnt waits (same-wave dependency)

        // ---- add srel (gather), online softmax ----
        float mnew[4];
        #pragma unroll
        for (int r = 0; r < 4; ++r) mnew[r] = m_i[r];
        #pragma unroll
        for (int js = 0; js < 4; ++js) {
            #pragma unroll
            for (int r = 0; r < 4; ++r) {
                int idx = js*16 + cl - (qd*4 + r) + 15;   // in [0, 78]
                float s = S[js][r] + sQE[w][qd*4 + r][idx];
                S[js][r] = s;
                mnew[r] = fmaxf(mnew[r], s);
            }
        }
        #pragma unroll
        for (int r = 0; r < 4; ++r) {
            float mv = mnew[r];
            mv = fmaxf(mv, __shfl_xor(mv, 1));
            mv = fmaxf(mv, __shfl_xor(mv, 2));
            mv = fmaxf(mv, __shfl_xor(mv, 4));
            mv = fmaxf(mv, __shfl_xor(mv, 8));
            mnew[r] = mv;
        }
        float alpha[4], rsum[4];
        #pragma unroll
        for (int r = 0; r < 4; ++r) {
            alpha[r] = expf((m_i[r] - mnew[r]) * scale);
            m_i[r] = mnew[r];
            rsum[r] = 0.f;
        }
        #pragma unroll
        for (int js = 0; js < 4; ++js) {
            #pragma unroll
            for (int r = 0; r < 4; ++r) {
                float p = expf((S[js][r] - m_i[r]) * scale);
                rsum[r] += p;
                sP[w][qd*4 + r][js*16 + cl] = __float2bfloat16(p);
            }
        }
        #pragma unroll
        for (int r = 0; r < 4; ++r) {
            float sv = rsum[r];
            sv += __shfl_xor(sv, 1);
            sv += __shfl_xor(sv, 2);
            sv += __shfl_xor(sv, 4);
            sv += __shfl_xor(sv, 8);
            l_i[r] = l_i[r]*alpha[r] + sv;
        }

        // ---- P A-frags (LDS round-trip C->A layout) ----
        bf16x8 pa0, pa1;
        {
            const bf16* pr = &sP[w][cl][0];
            #pragma unroll
            for (int e = 0; e < 8; ++e) ((short*)&pa0)[e] = ((const short*)pr)[qd*8 + e];
            #pragma unroll
            for (int e = 0; e < 8; ++e) ((short*)&pa1)[e] = ((const short*)pr)[32 + qd*8 + e];
        }

        // ---- O = O*alpha + P V ----
        #pragma unroll
        for (int nt = 0; nt < 4; ++nt) {
            #pragma unroll
            for (int r = 0; r < 4; ++r) Oacc[nt][r] *= alpha[r];
            bf16x8 vb0, vb1;
            const bf16* vr = &sVT[nt*16 + cl][0];
            #pragma unroll
            for (int e = 0; e < 8; ++e) ((short*)&vb0)[e] = ((const short*)vr)[qd*8 + e];
            #pragma unroll
            for (int e = 0; e < 8; ++e) ((short*)&vb1)[e] = ((const short*)vr)[32 + qd*8 + e];
            Oacc[nt] = __builtin_amdgcn_mfma_f32_16x16x32_bf16(pa0, vb0, Oacc[nt], 0, 0, 0);
            Oacc[nt] = __builtin_amdgcn_mfma_f32_16x16x32_bf16(pa1, vb1, Oacc[nt], 0, 0, 0);
        }
        __syncthreads();   // before next j-tile overwrites sVT
    }

    // ---- epilogue: O /= l, store ----
    #pragma unroll
    for (int nt = 0; nt < 4; ++nt) {
        #pragma unroll
        for (int r = 0; r < 4; ++r) {
            int row = qd*4 + r;
            float val = Oacc[nt][r] / l_i[r];
            o[bh + (size_t)(I + row)*DMODEL + nt*16 + cl] = __float2bfloat16(val);
        }
    }
}

// ---------------- output split + sigmoid (fp32 out) ----------------
__global__ __launch_bounds__(256)
void k_out(const float* __restrict__ y, float* __restrict__ out){
    int idx = blockIdx.x*256 + threadIdx.x;
    if (idx >= MTOK*73) return;
    int row = idx / 73, c = idx - row*73;
    float val = y[idx];
    if (c < DOF) out[(size_t)row*DOF + c] = val;
    else out[(size_t)MTOK*DOF + row*4 + (c-DOF)] = 1.f/(1.f + expf(-val));
}

extern "C" void kernel_launch(void* const* d_in, const int* in_sizes, int n_in,
                              void* d_out, int out_size, void* d_ws, size_t ws_size,
                              hipStream_t stream)
{
    fp32p x      = (fp32p)d_in[0];
    fp32p mask   = (fp32p)d_in[1];
    fp32p enc_w1 = (fp32p)d_in[2];
    fp32p enc_b1 = (fp32p)d_in[3];
    fp32p enc_a1 = (fp32p)d_in[4];
    fp32p enc_w2 = (fp32p)d_in[5];
    fp32p enc_b2 = (fp32p)d_in[6];
    fp32p enc_a2 = (fp32p)d_in[7];
    fp32p rel_w1 = (fp32p)d_in[8];
    fp32p rel_b1 = (fp32p)d_in[9];
    fp32p rel_a  = (fp32p)d_in[10];
    fp32p rel_w2 = (fp32p)d_in[11];
    fp32p rel_b2 = (fp32p)d_in[12];
    fp32p ln_g   = (fp32p)d_in[13];
    fp32p ln_b   = (fp32p)d_in[14];
    fp32p wq     = (fp32p)d_in[15];
    fp32p bq     = (fp32p)d_in[16];
    fp32p wk     = (fp32p)d_in[17];
    fp32p bk     = (fp32p)d_in[18];
    fp32p wv     = (fp32p)d_in[19];
    fp32p bv     = (fp32p)d_in[20];
    fp32p wo     = (fp32p)d_in[21];
    fp32p bo     = (fp32p)d_in[22];
    fp32p fw1    = (fp32p)d_in[23];
    fp32p fb1    = (fp32p)d_in[24];
    fp32p fa     = (fp32p)d_in[25];
    fp32p fw2    = (fp32p)d_in[26];
    fp32p fb2    = (fp32p)d_in[27];
    fp32p dec_w1 = (fp32p)d_in[28];
    fp32p dec_b1 = (fp32p)d_in[29];
    fp32p dec_a  = (fp32p)d_in[30];
    fp32p dec_w2 = (fp32p)d_in[31];
    fp32p dec_b2 = (fp32p)d_in[32];

    char* wsb = (char*)d_ws;
    bf16*  Ebf = (bf16*)(wsb + E_OFF);    // 1040 x 64 bf16 = 133 KB (fits in 508 KB gap)
    float* h   = (float*)(wsb + H_OFF);
    bf16*  hn  = (bf16*)(wsb + HN_OFF);
    bf16*  q   = (bf16*)(wsb + Q_OFF);
    bf16*  k   = (bf16*)(wsb + K_OFF);
    bf16*  v   = (bf16*)(wsb + V_OFF);
    bf16*  cat = q;            // encoder scratch
    bf16*  mid = q;            // ffn half, spans q+k slots (8 MB)
    bf16*  hb  = v;            // decoder bf16 cast of h
    float* y   = (float*)q;    // decoder logits fp32

    dim3 gD(DMODEL/64, MTOK/64);
    dim3 gF(1024/64, MTOK/64);

    // encoder
    k_concat<<<(MTOK*2*DOF+255)/256, 256, 0, stream>>>(x, mask, cat);
    k_gemm<1,0,1,0><<<gD,256,0,stream>>>(cat, 2*DOF, enc_w1, 0, DMODEL, enc_b1, 0, enc_a1, 0, nullptr, hn, DMODEL, MTOK, DMODEL, 2*DOF);
    k_gemm<1,0,1,1><<<gD,256,0,stream>>>(hn, DMODEL, enc_w2, 0, DMODEL, enc_b2, 0, enc_a2, 0, nullptr, h, DMODEL, MTOK, DMODEL, DMODEL);
    k_relemb<<<EROWS, 64, 0, stream>>>(rel_w1, rel_b1, rel_a, rel_w2, rel_b2, Ebf);

    for (int l = 0; l < NL; ++l) {
        size_t oW  = (size_t)l*DMODEL*DMODEL;
        size_t oB  = (size_t)l*DMODEL;
        size_t oF1 = (size_t)l*DMODEL*DFF;
        size_t oBF1= (size_t)l*DFF;
        size_t oF2 = (size_t)l*DFF*DMODEL;

        k_layernorm<<<MTOK, 256, 0, stream>>>(h, ln_g, ln_b, hn);
        k_gemm<0,0,1,0><<<gD,256,0,stream>>>(hn, DMODEL, wq, oW, DMODEL, bq, oB, nullptr, 0, nullptr, q, DMODEL, MTOK, DMODEL, DMODEL);
        k_gemm<0,0,1,0><<<gD,256,0,stream>>>(hn, DMODEL, wk, oW, DMODEL, bk, oB, nullptr, 0, nullptr, k, DMODEL, MTOK, DMODEL, DMODEL);
        k_gemm<0,0,1,0><<<gD,256,0,stream>>>(hn, DMODEL, wv, oW, DMODEL, bv, oB, nullptr, 0, nullptr, v, DMODEL, MTOK, DMODEL, DMODEL);
        k_attn<<<BB*NH*(TT/64), 256, 0, stream>>>(q, k, v, Ebf, hn);
        k_gemm<0,1,1,1><<<gD,256,0,stream>>>(hn, DMODEL, wo, oW, DMODEL, bo, oB, nullptr, 0, h, h, DMODEL, MTOK, DMODEL, DMODEL);
        k_layernorm<<<MTOK, 256, 0, stream>>>(h, ln_g, ln_b, hn);
        k_gemm<1,0,1,0><<<gF,256,0,stream>>>(hn, DMODEL, fw1, oF1, DFF, fb1, oBF1, fa, (size_t)l, nullptr, mid, 1024, MTOK, 1024, DMODEL);
        k_gemm<0,1,1,1><<<gD,256,0,stream>>>(mid, 1024, fw2, oF2, DMODEL, fb2, oB, nullptr, 0, h, h, DMODEL, MTOK, DMODEL, 1024);
        k_gemm<1,0,1,0><<<gF,256,0,stream>>>(hn, DMODEL, fw1, oF1 + 1024, DFF, fb1, oBF1 + 1024, fa, (size_t)l, nullptr, mid, 1024, MTOK, 1024, DMODEL);
        k_gemm<0,1,0,1><<<gD,256,0,stream>>>(mid, 1024, fw2, oF2 + (size_t)1024*DMODEL, DMODEL, nullptr, 0, nullptr, 0, h, h, DMODEL, MTOK, DMODEL, 1024);
    }

    // decoder
    k_cast<<<(MTOK*DMODEL+255)/256, 256, 0, stream>>>(h, hb);
    k_gemm<1,0,1,0><<<gD,256,0,stream>>>(hb, DMODEL, dec_w1, 0, DMODEL, dec_b1, 0, dec_a, 0, nullptr, hn, DMODEL, MTOK, DMODEL, DMODEL);
    {
        dim3 g2((DOF+4+63)/64, MTOK/64);
        k_gemm<0,0,1,1><<<g2,256,0,stream>>>(hn, DMODEL, dec_w2, 0, DOF+4, dec_b2, 0, nullptr, 0, nullptr, y, DOF+4, MTOK, DOF+4, DMODEL);
    }
    k_out<<<(MTOK*73+255)/256, 256, 0, stream>>>(y, (float*)d_out);
}